// Round 2
// baseline (1383.187 us; speedup 1.0000x reference)
//
#include <hip/hip_runtime.h>
#include <stdint.h>

#define BIGF 1e10f
#define T_LEN 1024
#define D_DIM 64
#define BATCH 32
#define L2E 1.4426950408889634f   /* log2(e) */
#define LN2F 0.6931471805599453f
#define BIG2 (1e10f * 1.4426950408889634f)   /* BIG in log2-scaled space */

#if defined(__has_builtin)
#if __has_builtin(__builtin_amdgcn_exp2f)
#define FAST_EXP2(x) __builtin_amdgcn_exp2f(x)
#endif
#if __has_builtin(__builtin_amdgcn_logf)
#define FAST_LOG2(x) __builtin_amdgcn_logf(x)   /* v_log_f32 = log2 */
#endif
#endif
#ifndef FAST_EXP2
#define FAST_EXP2(x) exp2f(x)
#endif
#ifndef FAST_LOG2
#define FAST_LOG2(x) log2f(x)
#endif

__device__ __forceinline__ unsigned short f2bf_rne(float f) {
    unsigned int u = __float_as_uint(f);
    u += 0x7fffu + ((u >> 16) & 1u);
    return (unsigned short)(u >> 16);
}

// ---------------------------------------------------------------------------
// Kernel 1: cost'[b][i][j] = max(0, x2_i + y2_j - 2*dot(x_i,y_j)) * log2(e),
// stored bf16. 64x64 tile / 256 threads / 4x4 microtile / K=64.
// ---------------------------------------------------------------------------
__global__ __launch_bounds__(256) void cost_gemm(const float* __restrict__ x,
                                                 const float* __restrict__ y,
                                                 unsigned short* __restrict__ cost) {
    __shared__ float As[D_DIM][68];
    __shared__ float Bs[D_DIM][68];
    __shared__ float x2s[64];
    __shared__ float y2s[64];

    const int b   = blockIdx.z;
    const int i0  = blockIdx.y * 64;
    const int j0  = blockIdx.x * 64;
    const int tid = threadIdx.x;
    const int tx  = tid & 15;
    const int ty  = tid >> 4;

    const float4* xt = (const float4*)(x + ((size_t)b * T_LEN + i0) * D_DIM);
    const float4* yt = (const float4*)(y + ((size_t)b * T_LEN + j0) * D_DIM);

    #pragma unroll
    for (int s = 0; s < 4; ++s) {
        int f   = tid + s * 256;
        int l   = f * 4;
        int row = l >> 6;
        int d0  = l & 63;
        float4 va = xt[f];
        float4 vb = yt[f];
        As[d0 + 0][row] = va.x; As[d0 + 1][row] = va.y;
        As[d0 + 2][row] = va.z; As[d0 + 3][row] = va.w;
        Bs[d0 + 0][row] = vb.x; Bs[d0 + 1][row] = vb.y;
        Bs[d0 + 2][row] = vb.z; Bs[d0 + 3][row] = vb.w;
    }
    __syncthreads();

    if (tid < 64) {
        float s = 0.f;
        #pragma unroll 16
        for (int d = 0; d < 64; ++d) { float v = As[d][tid]; s = fmaf(v, v, s); }
        x2s[tid] = s;
    } else if (tid < 128) {
        int t = tid - 64;
        float s = 0.f;
        #pragma unroll 16
        for (int d = 0; d < 64; ++d) { float v = Bs[d][t]; s = fmaf(v, v, s); }
        y2s[t] = s;
    }
    __syncthreads();

    float acc[4][4] = {};
    #pragma unroll 16
    for (int d = 0; d < 64; ++d) {
        float4 av = *(const float4*)&As[d][ty * 4];
        float4 bv = *(const float4*)&Bs[d][tx * 4];
        float ar[4] = {av.x, av.y, av.z, av.w};
        float br[4] = {bv.x, bv.y, bv.z, bv.w};
        #pragma unroll
        for (int r = 0; r < 4; ++r)
            #pragma unroll
            for (int c = 0; c < 4; ++c)
                acc[r][c] = fmaf(ar[r], br[c], acc[r][c]);
    }

    #pragma unroll
    for (int r = 0; r < 4; ++r) {
        float x2v = x2s[ty * 4 + r];
        float c0 = fmaxf(0.f, x2v + y2s[tx * 4 + 0] - 2.f * acc[r][0]) * L2E;
        float c1 = fmaxf(0.f, x2v + y2s[tx * 4 + 1] - 2.f * acc[r][1]) * L2E;
        float c2 = fmaxf(0.f, x2v + y2s[tx * 4 + 2] - 2.f * acc[r][2]) * L2E;
        float c3 = fmaxf(0.f, x2v + y2s[tx * 4 + 3] - 2.f * acc[r][3]) * L2E;
        ushort4 o;
        o.x = f2bf_rne(c0); o.y = f2bf_rne(c1); o.z = f2bf_rne(c2); o.w = f2bf_rne(c3);
        size_t off = ((size_t)b * T_LEN + (size_t)(i0 + ty * 4 + r)) * T_LEN + (size_t)(j0 + tx * 4);
        *(ushort4*)(cost + off) = o;
    }
}

// ---------------------------------------------------------------------------
// Kernel 2: barrier-free anti-diagonal DP. One wave (64 threads) per batch;
// thread t owns DP rows ii = 16t+1 .. 16t+16 in registers. Cross-thread
// boundary via __shfl_up; no __syncthreads anywhere.
// State is scaled by log2(e):  d' = d * L2E,  softmin' = m' - log2(1 + 2^(m'-mid') + 2^(m'-M')).
// Leading edge (col<0) uses pseudo-BIG propagation (drift negligible vs 1.44e10);
// trailing edge (col>1023) masked exactly to BIG2.
// k-loop covers k=2..2049 (256 x 8 substeps); answer is D2[15]@lane63 after loop.
// ---------------------------------------------------------------------------
__global__ __launch_bounds__(64) void dp_wave(const unsigned short* __restrict__ cost,
                                              float* __restrict__ out) {
    const int b = blockIdx.x;
    const int t = threadIdx.x;   // 0..63

    const unsigned short* rp[16];
    #pragma unroll
    for (int r = 0; r < 16; ++r)
        rp[r] = cost + ((size_t)(b * T_LEN + 16 * t + r)) * T_LEN;

    uint4 B[16], N[16];
    #pragma unroll
    for (int r = 0; r < 16; ++r) {
        N[r] = *(const uint4*)rp[r];           // preload quad cols 0..7
        B[r] = N[r];
    }

    float D1[16], D2[16];
    #pragma unroll
    for (int r = 0; r < 16; ++r) { D1[r] = BIG2; D2[r] = BIG2; }

    int c0s = -16 * t;                          // c0s = k - 2 - 16t at k=2

    for (int kb = 0; kb < 256; ++kb) {
        #pragma unroll
        for (int s = 0; s < 8; ++s) {
            float sh1 = __shfl_up(D1[15], 1);
            float sh2 = __shfl_up(D2[15], 1);
            if (t == 0) {
                sh1 = BIG2;
                sh2 = (s == 0 && kb == 0) ? 0.0f : BIG2;   // d_0[0] = 0 enters at k=2
            }
            float carry1 = sh1;   // d_{k-1}[ii-1] of previous row
            float carry2 = sh2;   // d_{k-2}[ii-1]
            #pragma unroll
            for (int r = 0; r < 16; ++r) {
                if (((s - r) & 7) == 0) {       // this row enters a new quad
                    B[r] = N[r];
                    int cl = c0s - r + 8;
                    cl = cl < 0 ? 0 : (cl > 1016 ? 1016 : cl);
                    N[r] = *(const uint4*)(rp[r] + cl);
                }
                const int e = (s - r) & 7;      // compile-time constant
                unsigned w = ((e >> 1) == 0) ? B[r].x :
                             ((e >> 1) == 1) ? B[r].y :
                             ((e >> 1) == 2) ? B[r].z : B[r].w;
                float cval = __uint_as_float((e & 1) ? (w & 0xffff0000u) : (w << 16));

                float a  = carry2;
                float bb = carry1;
                float cc = D1[r];
                float m   = fminf(fminf(a, bb), cc);
                float M   = fmaxf(fmaxf(a, bb), cc);
                float mid = __builtin_amdgcn_fmed3f(a, bb, cc);
                float ssum = 1.0f + FAST_EXP2(m - mid) + FAST_EXP2(m - M);
                float nv = cval + m - FAST_LOG2(ssum);
                nv = (c0s <= 1023 + r) ? nv : BIG2;   // trailing-edge exact mask

                carry2 = D2[r];
                carry1 = cc;
                D2[r] = cc;      // becomes d_{k-1}
                D1[r] = nv;      // becomes d_k
            }
            c0s += 1;
        }
    }
    // after k=2049: D1 = d_2049 (masked), D2 = d_2048. Answer: d_2048[1024].
    if (t == 63) out[b] = D2[15] * LN2F;        // descale from log2 space
}

// ---------------------------------------------------------------------------
// Fallback (no workspace): costs on the fly, unscaled space. Correct, slow.
// ---------------------------------------------------------------------------
__device__ __forceinline__ float softmin3_ref(float a, float b, float c) {
    float m = fminf(a, fminf(b, c));
    float s = FAST_EXP2((m - a) * L2E) + FAST_EXP2((m - b) * L2E) + FAST_EXP2((m - c) * L2E);
    return m - FAST_LOG2(s) * LN2F;
}

__global__ __launch_bounds__(1024) void dp_onthefly(const float* __restrict__ x,
                                                    const float* __restrict__ y,
                                                    float* __restrict__ out) {
    __shared__ float bufs[3][1026];
    __shared__ float y2s[1024];
    const int b   = blockIdx.x;
    const int tid = threadIdx.x;

    const float4* xrow = (const float4*)(x + ((size_t)b * T_LEN + (size_t)tid) * D_DIM);
    const float4* yb   = (const float4*)(y + (size_t)b * T_LEN * D_DIM);

    float4 xr[16];
    float x2 = 0.f;
    #pragma unroll
    for (int q = 0; q < 16; ++q) {
        xr[q] = xrow[q];
        x2 = fmaf(xr[q].x, xr[q].x, x2);
        x2 = fmaf(xr[q].y, xr[q].y, x2);
        x2 = fmaf(xr[q].z, xr[q].z, x2);
        x2 = fmaf(xr[q].w, xr[q].w, x2);
    }
    float y2 = 0.f;
    #pragma unroll
    for (int q = 0; q < 16; ++q) {
        float4 v = yb[tid * 16 + q];
        y2 = fmaf(v.x, v.x, y2); y2 = fmaf(v.y, v.y, y2);
        y2 = fmaf(v.z, v.z, y2); y2 = fmaf(v.w, v.w, y2);
    }
    y2s[tid] = y2;

    bufs[0][tid] = (tid == 0) ? 0.0f : BIGF;
    bufs[1][tid] = BIGF;
    if (tid == 0) { bufs[0][1024] = BIGF; bufs[1][1024] = BIGF; }
    __syncthreads();

    float* p2  = bufs[0];
    float* p1  = bufs[1];
    float* cur = bufs[2];

    for (int k = 2; k <= 2 * T_LEN; ++k) {
        const int col = k - tid - 2;
        float v = BIGF;
        if (col >= 0 && col < T_LEN) {
            const float4* yr = yb + (size_t)col * 16;
            float dot = 0.f;
            #pragma unroll
            for (int q = 0; q < 16; ++q) {
                float4 w = yr[q];
                dot = fmaf(xr[q].x, w.x, dot);
                dot = fmaf(xr[q].y, w.y, dot);
                dot = fmaf(xr[q].z, w.z, dot);
                dot = fmaf(xr[q].w, w.w, dot);
            }
            float cval = fmaxf(0.f, x2 + y2s[col] - 2.f * dot);
            v = cval + softmin3_ref(p2[tid], p1[tid], p1[tid + 1]);
        }
        cur[tid + 1] = v;
        if (tid == 0) cur[0] = BIGF;
        __syncthreads();
        float* tmp = p2; p2 = p1; p1 = cur; cur = tmp;
    }
    if (tid == 0) out[b] = p1[1024];
}

extern "C" void kernel_launch(void* const* d_in, const int* in_sizes, int n_in,
                              void* d_out, int out_size, void* d_ws, size_t ws_size,
                              hipStream_t stream) {
    const float* x = (const float*)d_in[0];
    const float* y = (const float*)d_in[1];
    float* out = (float*)d_out;

    const size_t cost_bytes = (size_t)BATCH * T_LEN * T_LEN * sizeof(unsigned short); // 64 MiB

    if (ws_size >= cost_bytes) {
        unsigned short* cost = (unsigned short*)d_ws;
        dim3 grid(T_LEN / 64, T_LEN / 64, BATCH);
        cost_gemm<<<grid, 256, 0, stream>>>(x, y, cost);
        dp_wave<<<BATCH, 64, 0, stream>>>(cost, out);
    } else {
        dp_onthefly<<<BATCH, 1024, 0, stream>>>(x, y, out);
    }
}

// Round 3
// 604.346 us; speedup vs baseline: 2.2887x; 2.2887x over previous
//
#include <hip/hip_runtime.h>
#include <stdint.h>

#define BIGF 1e10f
#define T_LEN 1024
#define D_DIM 64
#define BATCH 32
#define L2E 1.4426950408889634f   /* log2(e) */
#define LN2F 0.6931471805599453f
#define BIG2 (1e10f * 1.4426950408889634f)   /* BIG in log2-scaled space */

#if defined(__has_builtin)
#if __has_builtin(__builtin_amdgcn_exp2f)
#define FAST_EXP2(x) __builtin_amdgcn_exp2f(x)
#endif
#if __has_builtin(__builtin_amdgcn_logf)
#define FAST_LOG2(x) __builtin_amdgcn_logf(x)   /* v_log_f32 = log2 */
#endif
#endif
#ifndef FAST_EXP2
#define FAST_EXP2(x) exp2f(x)
#endif
#ifndef FAST_LOG2
#define FAST_LOG2(x) log2f(x)
#endif

__device__ __forceinline__ unsigned short f2bf_rne(float f) {
    unsigned int u = __float_as_uint(f);
    u += 0x7fffu + ((u >> 16) & 1u);
    return (unsigned short)(u >> 16);
}

__device__ __forceinline__ unsigned qd(const uint4& q, int i) {
    return i == 0 ? q.x : i == 1 ? q.y : i == 2 ? q.z : q.w;   // folds for constant i
}

// ---------------------------------------------------------------------------
// Kernel 1 (unchanged): cost'[b][i][j] = max(0, ||x_i-y_j||^2) * log2(e), bf16.
// ---------------------------------------------------------------------------
__global__ __launch_bounds__(256) void cost_gemm(const float* __restrict__ x,
                                                 const float* __restrict__ y,
                                                 unsigned short* __restrict__ cost) {
    __shared__ float As[D_DIM][68];
    __shared__ float Bs[D_DIM][68];
    __shared__ float x2s[64];
    __shared__ float y2s[64];

    const int b   = blockIdx.z;
    const int i0  = blockIdx.y * 64;
    const int j0  = blockIdx.x * 64;
    const int tid = threadIdx.x;
    const int tx  = tid & 15;
    const int ty  = tid >> 4;

    const float4* xt = (const float4*)(x + ((size_t)b * T_LEN + i0) * D_DIM);
    const float4* yt = (const float4*)(y + ((size_t)b * T_LEN + j0) * D_DIM);

    #pragma unroll
    for (int s = 0; s < 4; ++s) {
        int f   = tid + s * 256;
        int l   = f * 4;
        int row = l >> 6;
        int d0  = l & 63;
        float4 va = xt[f];
        float4 vb = yt[f];
        As[d0 + 0][row] = va.x; As[d0 + 1][row] = va.y;
        As[d0 + 2][row] = va.z; As[d0 + 3][row] = va.w;
        Bs[d0 + 0][row] = vb.x; Bs[d0 + 1][row] = vb.y;
        Bs[d0 + 2][row] = vb.z; Bs[d0 + 3][row] = vb.w;
    }
    __syncthreads();

    if (tid < 64) {
        float s = 0.f;
        #pragma unroll 16
        for (int d = 0; d < 64; ++d) { float v = As[d][tid]; s = fmaf(v, v, s); }
        x2s[tid] = s;
    } else if (tid < 128) {
        int t = tid - 64;
        float s = 0.f;
        #pragma unroll 16
        for (int d = 0; d < 64; ++d) { float v = Bs[d][t]; s = fmaf(v, v, s); }
        y2s[t] = s;
    }
    __syncthreads();

    float acc[4][4] = {};
    #pragma unroll 16
    for (int d = 0; d < 64; ++d) {
        float4 av = *(const float4*)&As[d][ty * 4];
        float4 bv = *(const float4*)&Bs[d][tx * 4];
        float ar[4] = {av.x, av.y, av.z, av.w};
        float br[4] = {bv.x, bv.y, bv.z, bv.w};
        #pragma unroll
        for (int r = 0; r < 4; ++r)
            #pragma unroll
            for (int c = 0; c < 4; ++c)
                acc[r][c] = fmaf(ar[r], br[c], acc[r][c]);
    }

    #pragma unroll
    for (int r = 0; r < 4; ++r) {
        float x2v = x2s[ty * 4 + r];
        float c0 = fmaxf(0.f, x2v + y2s[tx * 4 + 0] - 2.f * acc[r][0]) * L2E;
        float c1 = fmaxf(0.f, x2v + y2s[tx * 4 + 1] - 2.f * acc[r][1]) * L2E;
        float c2 = fmaxf(0.f, x2v + y2s[tx * 4 + 2] - 2.f * acc[r][2]) * L2E;
        float c3 = fmaxf(0.f, x2v + y2s[tx * 4 + 3] - 2.f * acc[r][3]) * L2E;
        ushort4 o;
        o.x = f2bf_rne(c0); o.y = f2bf_rne(c1); o.z = f2bf_rne(c2); o.w = f2bf_rne(c3);
        size_t off = ((size_t)b * T_LEN + (size_t)(i0 + ty * 4 + r)) * T_LEN + (size_t)(j0 + tx * 4);
        *(ushort4*)(cost + off) = o;
    }
}

// ---------------------------------------------------------------------------
// Kernel 2: systolic 4-wave pipeline per batch (1 block = 256 thr = 4 waves).
// Wave w owns DP rows 256w+1 .. 256w+256 (4 rows/lane, registers).
// Intra-wave neighbor via __shfl_up; inter-wave boundary history in LDS,
// handed off in 8-diagonal chunks with per-wave progress flags (no barriers
// after init). Producer runs 33 chunks ahead of its consumer.
// State scaled by log2(e); leading edge = pseudo-BIG propagation, trailing
// edge exactly masked. Answer = d_2048[1024] at wave 3, lane 63, r=3.
// ---------------------------------------------------------------------------
__global__ __launch_bounds__(256) void dp_pipe(const unsigned short* __restrict__ cost,
                                               float* __restrict__ out) {
    __shared__ float Bnd[3][2064];   // boundary history, indexed by absolute k
    __shared__ int   prog[4];

    const int b   = blockIdx.x;
    const int tid = threadIdx.x;
    const int w   = tid >> 6;        // wave 0..3
    const int l   = tid & 63;        // lane
    const int p   = l & 1;           // parity (phase select)

    for (int j = tid; j < 3 * 2064; j += 256) ((float*)Bnd)[j] = BIG2;
    if (tid < 4) prog[tid] = 0;
    __syncthreads();                 // only barrier; uniform for all threads

    volatile int* progv = prog;

    // cost row pointers: rows ri = 256w + 4l + r
    const unsigned short* rp[4];
    #pragma unroll
    for (int r = 0; r < 4; ++r)
        rp[r] = cost + ((size_t)(b * T_LEN + 256 * w + 4 * l + r)) * T_LEN;

    uint4 Bq[4], Nq[4], Pq[4];
    #pragma unroll
    for (int r = 0; r < 4; ++r) { Bq[r] = *(const uint4*)rp[r]; Nq[r] = Bq[r]; }

    float D1[4], D2[4];              // d_{k-1}[i_r], d_{k-2}[i_r]
    #pragma unroll
    for (int r = 0; r < 4; ++r) { D1[r] = BIG2; D2[r] = BIG2; }

    float pv[9];
    #pragma unroll
    for (int j = 0; j < 9; ++j) pv[j] = BIG2;
    float bval[8];

    const int thr_base = 4 * l + 1023;   // trailing-valid: 8c+s <= thr_base + r

    for (int c = 0; c < 160; ++c) {
        const int k0 = 256 * w + 2 + 8 * c;

        // prefetch quads for chunk c+1 (consumed >= 8 substeps later)
        int qn = c + 1 - (l >> 1);
        qn = qn < 0 ? 0 : (qn > 127 ? 127 : qn);
        #pragma unroll
        for (int r = 0; r < 4; ++r) Pq[r] = *(const uint4*)(rp[r] + qn * 8);

        if (w > 0) {
            int need = c + 33; if (need > 160) need = 160;
            while (progv[w - 1] < need) { }
            __threadfence_block();
            #pragma unroll
            for (int j = 0; j < 9; ++j) pv[j] = Bnd[w - 1][k0 - 2 + j];
        }

        #pragma unroll
        for (int s = 0; s < 8; ++s) {
            float sh1 = __shfl_up(D1[3], 1);   // prev lane's bottom row, d_{k-1}
            float sh2 = __shfl_up(D2[3], 1);   // d_{k-2}
            float a_in, b_in;
            if (w == 0) {
                a_in = (c == 0 && s == 0) ? 0.0f : BIG2;  // d_0[0]=0 enters at k=2
                b_in = BIG2;
            } else {
                a_in = pv[s];       // d_{k-2}[256w]
                b_in = pv[s + 1];   // d_{k-1}[256w]
            }
            float carry2 = (l == 0) ? a_in : sh2;
            float carry1 = (l == 0) ? b_in : sh1;

            #pragma unroll
            for (int r = 0; r < 4; ++r) {
                // bf16 cost extract; col = 8c - 4l - r + s, phase r+4p
                const int e0  = (s - r) & 7;
                const int d0i = e0 >> 1;
                const int d1i = d0i ^ 2;
                const int hf  = e0 & 1;
                unsigned w0 = (s >= r)     ? qd(Nq[r], d0i) : qd(Bq[r], d0i);
                unsigned w1 = (s >= r + 4) ? qd(Nq[r], d1i) : qd(Bq[r], d1i);
                unsigned ws = p ? w1 : w0;
                float cval = __uint_as_float(hf ? (ws & 0xffff0000u) : (ws << 16));

                float aa = carry2, bb = carry1, cc = D1[r];
                float m   = fminf(fminf(aa, bb), cc);
                float M   = fmaxf(fmaxf(aa, bb), cc);
                float mid = __builtin_amdgcn_fmed3f(aa, bb, cc);
                float ssum = 1.0f + FAST_EXP2(m - mid) + FAST_EXP2(m - M);
                float nv = cval + m - FAST_LOG2(ssum);
                nv = ((8 * c + s) <= (thr_base + r)) ? nv : BIG2;  // trailing mask

                carry2 = D2[r];
                carry1 = cc;
                D2[r] = cc;
                D1[r] = nv;
            }
            bval[s] = D1[3];
        }

        if (w < 3) {                       // publish boundary history
            if (l == 63) {
                #pragma unroll
                for (int s = 0; s < 8; ++s) Bnd[w][k0 + s] = bval[s];
            }
            __threadfence_block();
            if (l == 63) progv[w] = c + 1;
        }

        #pragma unroll
        for (int r = 0; r < 4; ++r) { Bq[r] = Nq[r]; Nq[r] = Pq[r]; }
    }

    if (w == 3 && l == 63) out[b] = D2[3] * LN2F;   // d_2048[1024], descaled
}

// ---------------------------------------------------------------------------
// Fallback (no workspace): costs on the fly. Correct, slow.
// ---------------------------------------------------------------------------
__device__ __forceinline__ float softmin3_ref(float a, float b, float c) {
    float m = fminf(a, fminf(b, c));
    float s = FAST_EXP2((m - a) * L2E) + FAST_EXP2((m - b) * L2E) + FAST_EXP2((m - c) * L2E);
    return m - FAST_LOG2(s) * LN2F;
}

__global__ __launch_bounds__(1024) void dp_onthefly(const float* __restrict__ x,
                                                    const float* __restrict__ y,
                                                    float* __restrict__ out) {
    __shared__ float bufs[3][1026];
    __shared__ float y2s[1024];
    const int b   = blockIdx.x;
    const int tid = threadIdx.x;

    const float4* xrow = (const float4*)(x + ((size_t)b * T_LEN + (size_t)tid) * D_DIM);
    const float4* yb   = (const float4*)(y + (size_t)b * T_LEN * D_DIM);

    float4 xr[16];
    float x2 = 0.f;
    #pragma unroll
    for (int q = 0; q < 16; ++q) {
        xr[q] = xrow[q];
        x2 = fmaf(xr[q].x, xr[q].x, x2);
        x2 = fmaf(xr[q].y, xr[q].y, x2);
        x2 = fmaf(xr[q].z, xr[q].z, x2);
        x2 = fmaf(xr[q].w, xr[q].w, x2);
    }
    float y2 = 0.f;
    #pragma unroll
    for (int q = 0; q < 16; ++q) {
        float4 v = yb[tid * 16 + q];
        y2 = fmaf(v.x, v.x, y2); y2 = fmaf(v.y, v.y, y2);
        y2 = fmaf(v.z, v.z, y2); y2 = fmaf(v.w, v.w, y2);
    }
    y2s[tid] = y2;

    bufs[0][tid] = (tid == 0) ? 0.0f : BIGF;
    bufs[1][tid] = BIGF;
    if (tid == 0) { bufs[0][1024] = BIGF; bufs[1][1024] = BIGF; }
    __syncthreads();

    float* p2  = bufs[0];
    float* p1  = bufs[1];
    float* cur = bufs[2];

    for (int k = 2; k <= 2 * T_LEN; ++k) {
        const int col = k - tid - 2;
        float v = BIGF;
        if (col >= 0 && col < T_LEN) {
            const float4* yr = yb + (size_t)col * 16;
            float dot = 0.f;
            #pragma unroll
            for (int q = 0; q < 16; ++q) {
                float4 ww = yr[q];
                dot = fmaf(xr[q].x, ww.x, dot);
                dot = fmaf(xr[q].y, ww.y, dot);
                dot = fmaf(xr[q].z, ww.z, dot);
                dot = fmaf(xr[q].w, ww.w, dot);
            }
            float cval = fmaxf(0.f, x2 + y2s[col] - 2.f * dot);
            v = cval + softmin3_ref(p2[tid], p1[tid], p1[tid + 1]);
        }
        cur[tid + 1] = v;
        if (tid == 0) cur[0] = BIGF;
        __syncthreads();
        float* tmp = p2; p2 = p1; p1 = cur; cur = tmp;
    }
    if (tid == 0) out[b] = p1[1024];
}

extern "C" void kernel_launch(void* const* d_in, const int* in_sizes, int n_in,
                              void* d_out, int out_size, void* d_ws, size_t ws_size,
                              hipStream_t stream) {
    const float* x = (const float*)d_in[0];
    const float* y = (const float*)d_in[1];
    float* out = (float*)d_out;

    const size_t cost_bytes = (size_t)BATCH * T_LEN * T_LEN * sizeof(unsigned short); // 64 MiB

    if (ws_size >= cost_bytes) {
        unsigned short* cost = (unsigned short*)d_ws;
        dim3 grid(T_LEN / 64, T_LEN / 64, BATCH);
        cost_gemm<<<grid, 256, 0, stream>>>(x, y, cost);
        dp_pipe<<<BATCH, 256, 0, stream>>>(cost, out);
    } else {
        dp_onthefly<<<BATCH, 1024, 0, stream>>>(x, y, out);
    }
}

// Round 4
// 473.599 us; speedup vs baseline: 2.9206x; 1.2761x over previous
//
#include <hip/hip_runtime.h>
#include <stdint.h>

#define BIGF 1e10f
#define T_LEN 1024
#define D_DIM 64
#define BATCH 32
#define L2E 1.4426950408889634f   /* log2(e) */
#define LN2F 0.6931471805599453f
#define BIG2 (1e10f * 1.4426950408889634f)   /* BIG in log2-scaled space */
#define NCHUNK 144                /* chunks per wave: (1024+128)/8 */
#define NOMASK_CHUNKS 127         /* for c<127: 8c+7 <= 1015 < 1023+2l+r  */

#if defined(__has_builtin)
#if __has_builtin(__builtin_amdgcn_exp2f)
#define FAST_EXP2(x) __builtin_amdgcn_exp2f(x)
#endif
#if __has_builtin(__builtin_amdgcn_logf)
#define FAST_LOG2(x) __builtin_amdgcn_logf(x)   /* v_log_f32 = log2 */
#endif
#endif
#ifndef FAST_EXP2
#define FAST_EXP2(x) exp2f(x)
#endif
#ifndef FAST_LOG2
#define FAST_LOG2(x) log2f(x)
#endif

__device__ __forceinline__ unsigned short f2bf_rne(float f) {
    unsigned int u = __float_as_uint(f);
    u += 0x7fffu + ((u >> 16) & 1u);
    return (unsigned short)(u >> 16);
}

__device__ __forceinline__ unsigned qd(const uint4& q, int i) {
    return i == 0 ? q.x : i == 1 ? q.y : i == 2 ? q.z : q.w;   // folds for constant i
}
__device__ __forceinline__ unsigned wsel(const uint4& B, const uint4& N, int j) {
    return j < 4 ? qd(B, j) : qd(N, j - 4);                     // folds for constant j
}

// ---------------------------------------------------------------------------
// Kernel 1 (unchanged): cost'[b][i][j] = max(0, ||x_i-y_j||^2) * log2(e), bf16.
// ---------------------------------------------------------------------------
__global__ __launch_bounds__(256) void cost_gemm(const float* __restrict__ x,
                                                 const float* __restrict__ y,
                                                 unsigned short* __restrict__ cost) {
    __shared__ float As[D_DIM][68];
    __shared__ float Bs[D_DIM][68];
    __shared__ float x2s[64];
    __shared__ float y2s[64];

    const int b   = blockIdx.z;
    const int i0  = blockIdx.y * 64;
    const int j0  = blockIdx.x * 64;
    const int tid = threadIdx.x;
    const int tx  = tid & 15;
    const int ty  = tid >> 4;

    const float4* xt = (const float4*)(x + ((size_t)b * T_LEN + i0) * D_DIM);
    const float4* yt = (const float4*)(y + ((size_t)b * T_LEN + j0) * D_DIM);

    #pragma unroll
    for (int s = 0; s < 4; ++s) {
        int f   = tid + s * 256;
        int l   = f * 4;
        int row = l >> 6;
        int d0  = l & 63;
        float4 va = xt[f];
        float4 vb = yt[f];
        As[d0 + 0][row] = va.x; As[d0 + 1][row] = va.y;
        As[d0 + 2][row] = va.z; As[d0 + 3][row] = va.w;
        Bs[d0 + 0][row] = vb.x; Bs[d0 + 1][row] = vb.y;
        Bs[d0 + 2][row] = vb.z; Bs[d0 + 3][row] = vb.w;
    }
    __syncthreads();

    if (tid < 64) {
        float s = 0.f;
        #pragma unroll 16
        for (int d = 0; d < 64; ++d) { float v = As[d][tid]; s = fmaf(v, v, s); }
        x2s[tid] = s;
    } else if (tid < 128) {
        int t = tid - 64;
        float s = 0.f;
        #pragma unroll 16
        for (int d = 0; d < 64; ++d) { float v = Bs[d][t]; s = fmaf(v, v, s); }
        y2s[t] = s;
    }
    __syncthreads();

    float acc[4][4] = {};
    #pragma unroll 16
    for (int d = 0; d < 64; ++d) {
        float4 av = *(const float4*)&As[d][ty * 4];
        float4 bv = *(const float4*)&Bs[d][tx * 4];
        float ar[4] = {av.x, av.y, av.z, av.w};
        float br[4] = {bv.x, bv.y, bv.z, bv.w};
        #pragma unroll
        for (int r = 0; r < 4; ++r)
            #pragma unroll
            for (int c = 0; c < 4; ++c)
                acc[r][c] = fmaf(ar[r], br[c], acc[r][c]);
    }

    #pragma unroll
    for (int r = 0; r < 4; ++r) {
        float x2v = x2s[ty * 4 + r];
        float c0 = fmaxf(0.f, x2v + y2s[tx * 4 + 0] - 2.f * acc[r][0]) * L2E;
        float c1 = fmaxf(0.f, x2v + y2s[tx * 4 + 1] - 2.f * acc[r][1]) * L2E;
        float c2 = fmaxf(0.f, x2v + y2s[tx * 4 + 2] - 2.f * acc[r][2]) * L2E;
        float c3 = fmaxf(0.f, x2v + y2s[tx * 4 + 3] - 2.f * acc[r][3]) * L2E;
        ushort4 o;
        o.x = f2bf_rne(c0); o.y = f2bf_rne(c1); o.z = f2bf_rne(c2); o.w = f2bf_rne(c3);
        size_t off = ((size_t)b * T_LEN + (size_t)(i0 + ty * 4 + r)) * T_LEN + (size_t)(j0 + tx * 4);
        *(ushort4*)(cost + off) = o;
    }
}

// ---------------------------------------------------------------------------
// Kernel 2: systolic 8-wave pipeline per batch (512 thr = 2 waves/SIMD for
// latency hiding). Wave w owns rows 128w+1..128w+128 (2 rows/lane). Intra-wave
// neighbor via __shfl_up; inter-wave boundary history in LDS with per-wave
// progress flags (no barriers after init). Chunk = 8 diagonals; consumer needs
// producer 17 chunks ahead. State scaled by log2(e).
// Row of lane l: i = 128w + 2l + r + 1. col(k) = 8c + s - 2l - r.
// Window = [Bq|Nq] = quads (c-(l>>2)-1, c-(l>>2)); element idx = 8+(s-r)-2(l&3)
// in [1,15]; dword j = ((8+s-r)>>1) - (l&3); half = (s-r)&1 (compile-time).
// ---------------------------------------------------------------------------
template<bool MASK, bool W0>
__device__ __forceinline__ void run_range(
    int cbeg, int cend, int l, int phi, int q0,
    const unsigned short* __restrict__ rp0,
    const unsigned short* __restrict__ rp1,
    uint4 (&Bq)[2], uint4 (&Nq)[2],
    float (&D1)[2], float (&D2)[2], int thr_base,
    float* __restrict__ bnd_out, const float* __restrict__ bnd_in,
    volatile int* flag_out, volatile int* flag_in)
{
    for (int c = cbeg; c < cend; ++c) {
        // prefetch quads for chunk c+1
        int qn = c + 1 - q0;
        qn = qn < 0 ? 0 : (qn > 127 ? 127 : qn);
        uint4 Pq0 = *(const uint4*)(rp0 + qn * 8);
        uint4 Pq1 = *(const uint4*)(rp1 + qn * 8);

        float pv[9];
        if (!W0) {
            int need = c + 17; if (need > NCHUNK) need = NCHUNK;
            while (*flag_in < need) { __builtin_amdgcn_s_sleep(2); }
            __threadfence_block();
            #pragma unroll
            for (int j = 0; j < 9; ++j) pv[j] = bnd_in[8 * c + 126 + j];
        }

        float bval[8];
        #pragma unroll
        for (int s = 0; s < 8; ++s) {
            float sh1 = __shfl_up(D1[1], 1);
            float sh2 = __shfl_up(D2[1], 1);
            float a_in, b_in;
            if (W0) {
                a_in = (c == 0 && s == 0) ? 0.0f : BIG2;   // d_0[0]=0 enters at k=2
                b_in = BIG2;
            } else {
                a_in = pv[s];       // d_{k-2}[128w]
                b_in = pv[s + 1];   // d_{k-1}[128w]
            }
            float carry2 = (l == 0) ? a_in : sh2;
            float carry1 = (l == 0) ? b_in : sh1;

            #pragma unroll
            for (int r = 0; r < 2; ++r) {
                const int J0 = (8 + s - r) >> 1;     // 3..7, compile-time
                const int hf = (s - r) & 1;          // compile-time
                unsigned e0 = wsel(Bq[r], Nq[r], J0);
                unsigned e1 = wsel(Bq[r], Nq[r], J0 - 1);
                unsigned e2 = wsel(Bq[r], Nq[r], J0 - 2);
                unsigned e3 = wsel(Bq[r], Nq[r], J0 - 3);
                unsigned t0 = (phi & 1) ? e1 : e0;
                unsigned t1 = (phi & 1) ? e3 : e2;
                unsigned wsv = (phi & 2) ? t1 : t0;
                float cval = __uint_as_float(hf ? (wsv & 0xffff0000u) : (wsv << 16));

                float aa = carry2, bb = carry1, cc = D1[r];
                float m   = fminf(fminf(aa, bb), cc);
                float M   = fmaxf(fmaxf(aa, bb), cc);
                float mid = __builtin_amdgcn_fmed3f(aa, bb, cc);
                float ssum = 1.0f + FAST_EXP2(m - mid) + FAST_EXP2(m - M);
                float nv = cval + m - FAST_LOG2(ssum);
                if (MASK) nv = ((8 * c + s) <= (thr_base + r)) ? nv : BIG2;

                carry2 = D2[r];
                carry1 = cc;
                D2[r] = cc;
                D1[r] = nv;
            }
            bval[s] = D1[1];
        }

        if (bnd_out) {                     // wave < 7: publish boundary row
            if (l == 63) {
                #pragma unroll
                for (int s = 0; s < 8; ++s) bnd_out[8 * c + s] = bval[s];
            }
            __threadfence_block();
            if (l == 63) *flag_out = c + 1;
        }

        Bq[0] = Nq[0]; Bq[1] = Nq[1];
        Nq[0] = Pq0;   Nq[1] = Pq1;
    }
}

__global__ __launch_bounds__(512) void dp_pipe8(const unsigned short* __restrict__ cost,
                                                float* __restrict__ out) {
    __shared__ float Bnd[7][1280];   // [producer wave][k - (128w+2)], init BIG2
    __shared__ int   prog[8];

    const int b   = blockIdx.x;
    const int tid = threadIdx.x;
    const int w   = tid >> 6;        // wave 0..7
    const int l   = tid & 63;
    const int phi = l & 3;
    const int q0  = l >> 2;

    for (int j = tid; j < 7 * 1280; j += 512) ((float*)Bnd)[j] = BIG2;
    if (tid < 8) prog[tid] = 0;
    __syncthreads();                 // only barrier

    volatile int* progv = prog;

    const unsigned short* rp0 = cost + ((size_t)(b * T_LEN + 128 * w + 2 * l)) * T_LEN;
    const unsigned short* rp1 = rp0 + T_LEN;

    uint4 Bq[2], Nq[2];
    Nq[0] = *(const uint4*)rp0;      // quad 0 (clamped window start)
    Nq[1] = *(const uint4*)rp1;
    Bq[0] = Nq[0]; Bq[1] = Nq[1];

    float D1[2] = {BIG2, BIG2}, D2[2] = {BIG2, BIG2};
    const int thr_base = 2 * l + 1023;   // valid iff 8c+s <= thr_base + r

    float* bnd_out = (w < 7) ? Bnd[w] : nullptr;
    const float* bnd_in = (w > 0) ? Bnd[w - 1] : nullptr;
    volatile int* flag_out = &progv[w];
    volatile int* flag_in  = (w > 0) ? &progv[w - 1] : nullptr;

    if (w == 0) {
        run_range<false, true>(0, NOMASK_CHUNKS, l, phi, q0, rp0, rp1, Bq, Nq, D1, D2,
                               thr_base, bnd_out, bnd_in, flag_out, flag_in);
        run_range<true,  true>(NOMASK_CHUNKS, NCHUNK, l, phi, q0, rp0, rp1, Bq, Nq, D1, D2,
                               thr_base, bnd_out, bnd_in, flag_out, flag_in);
    } else {
        run_range<false, false>(0, NOMASK_CHUNKS, l, phi, q0, rp0, rp1, Bq, Nq, D1, D2,
                                thr_base, bnd_out, bnd_in, flag_out, flag_in);
        run_range<true,  false>(NOMASK_CHUNKS, NCHUNK, l, phi, q0, rp0, rp1, Bq, Nq, D1, D2,
                                thr_base, bnd_out, bnd_in, flag_out, flag_in);
    }

    // after k = 128*7+1153 = 2049: D1 = d_2049 (masked), D2 = d_2048.
    if (w == 7 && l == 63) out[b] = D2[1] * LN2F;   // d_2048[1024], descaled
}

// ---------------------------------------------------------------------------
// Fallback (no workspace): costs on the fly. Correct, slow.
// ---------------------------------------------------------------------------
__device__ __forceinline__ float softmin3_ref(float a, float b, float c) {
    float m = fminf(a, fminf(b, c));
    float s = FAST_EXP2((m - a) * L2E) + FAST_EXP2((m - b) * L2E) + FAST_EXP2((m - c) * L2E);
    return m - FAST_LOG2(s) * LN2F;
}

__global__ __launch_bounds__(1024) void dp_onthefly(const float* __restrict__ x,
                                                    const float* __restrict__ y,
                                                    float* __restrict__ out) {
    __shared__ float bufs[3][1026];
    __shared__ float y2s[1024];
    const int b   = blockIdx.x;
    const int tid = threadIdx.x;

    const float4* xrow = (const float4*)(x + ((size_t)b * T_LEN + (size_t)tid) * D_DIM);
    const float4* yb   = (const float4*)(y + (size_t)b * T_LEN * D_DIM);

    float4 xr[16];
    float x2 = 0.f;
    #pragma unroll
    for (int q = 0; q < 16; ++q) {
        xr[q] = xrow[q];
        x2 = fmaf(xr[q].x, xr[q].x, x2);
        x2 = fmaf(xr[q].y, xr[q].y, x2);
        x2 = fmaf(xr[q].z, xr[q].z, x2);
        x2 = fmaf(xr[q].w, xr[q].w, x2);
    }
    float y2 = 0.f;
    #pragma unroll
    for (int q = 0; q < 16; ++q) {
        float4 v = yb[tid * 16 + q];
        y2 = fmaf(v.x, v.x, y2); y2 = fmaf(v.y, v.y, y2);
        y2 = fmaf(v.z, v.z, y2); y2 = fmaf(v.w, v.w, y2);
    }
    y2s[tid] = y2;

    bufs[0][tid] = (tid == 0) ? 0.0f : BIGF;
    bufs[1][tid] = BIGF;
    if (tid == 0) { bufs[0][1024] = BIGF; bufs[1][1024] = BIGF; }
    __syncthreads();

    float* p2  = bufs[0];
    float* p1  = bufs[1];
    float* cur = bufs[2];

    for (int k = 2; k <= 2 * T_LEN; ++k) {
        const int col = k - tid - 2;
        float v = BIGF;
        if (col >= 0 && col < T_LEN) {
            const float4* yr = yb + (size_t)col * 16;
            float dot = 0.f;
            #pragma unroll
            for (int q = 0; q < 16; ++q) {
                float4 ww = yr[q];
                dot = fmaf(xr[q].x, ww.x, dot);
                dot = fmaf(xr[q].y, ww.y, dot);
                dot = fmaf(xr[q].z, ww.z, dot);
                dot = fmaf(xr[q].w, ww.w, dot);
            }
            float cval = fmaxf(0.f, x2 + y2s[col] - 2.f * dot);
            v = cval + softmin3_ref(p2[tid], p1[tid], p1[tid + 1]);
        }
        cur[tid + 1] = v;
        if (tid == 0) cur[0] = BIGF;
        __syncthreads();
        float* tmp = p2; p2 = p1; p1 = cur; cur = tmp;
    }
    if (tid == 0) out[b] = p1[1024];
}

extern "C" void kernel_launch(void* const* d_in, const int* in_sizes, int n_in,
                              void* d_out, int out_size, void* d_ws, size_t ws_size,
                              hipStream_t stream) {
    const float* x = (const float*)d_in[0];
    const float* y = (const float*)d_in[1];
    float* out = (float*)d_out;

    const size_t cost_bytes = (size_t)BATCH * T_LEN * T_LEN * sizeof(unsigned short); // 64 MiB

    if (ws_size >= cost_bytes) {
        unsigned short* cost = (unsigned short*)d_ws;
        dim3 grid(T_LEN / 64, T_LEN / 64, BATCH);
        cost_gemm<<<grid, 256, 0, stream>>>(x, y, cost);
        dp_pipe8<<<BATCH, 512, 0, stream>>>(cost, out);
    } else {
        dp_onthefly<<<BATCH, 1024, 0, stream>>>(x, y, out);
    }
}

// Round 6
// 388.000 us; speedup vs baseline: 3.5649x; 1.2206x over previous
//
#include <hip/hip_runtime.h>
#include <stdint.h>

#define BIGF 1e10f
#define T_LEN 1024
#define D_DIM 64
#define BATCH 32
#define L2E 1.4426950408889634f   /* log2(e) */
#define LN2F 0.6931471805599453f
#define BIG2 (1e10f * 1.4426950408889634f)   /* BIG in log2-scaled space */
#define NCHUNK 144                /* chunks per wave: (1024+128)/8 */
#define NOMASK_CHUNKS 127         /* for c<127: 8c+7 <= 1015 < 1023+2l+r  */

#if defined(__has_builtin)
#if __has_builtin(__builtin_amdgcn_exp2f)
#define FAST_EXP2(x) __builtin_amdgcn_exp2f(x)
#endif
#if __has_builtin(__builtin_amdgcn_logf)
#define FAST_LOG2(x) __builtin_amdgcn_logf(x)   /* v_log_f32 = log2 */
#endif
#endif
#ifndef FAST_EXP2
#define FAST_EXP2(x) exp2f(x)
#endif
#ifndef FAST_LOG2
#define FAST_LOG2(x) log2f(x)
#endif

typedef __attribute__((ext_vector_type(8))) short short8;
typedef __attribute__((ext_vector_type(4))) float floatx4;

__device__ __forceinline__ unsigned short f2bf_rne(float f) {
    unsigned int u = __float_as_uint(f);
    u += 0x7fffu + ((u >> 16) & 1u);
    return (unsigned short)(u >> 16);
}

__device__ __forceinline__ float bf_lo(unsigned u) { return __uint_as_float(u << 16); }
__device__ __forceinline__ float bf_hi(unsigned u) { return __uint_as_float(u & 0xffff0000u); }

__device__ __forceinline__ unsigned qd(const uint4& q, int i) {
    return i == 0 ? q.x : i == 1 ? q.y : i == 2 ? q.z : q.w;   // folds for constant i
}
__device__ __forceinline__ unsigned wsel(const uint4& B, const uint4& N, int j) {
    return j < 4 ? qd(B, j) : qd(N, j - 4);                     // folds for constant j
}

// lane l gets src from lane l-1; lane 0 gets old0.
// dpp_ctrl 0x138 = wave_shr:1 (data moves to HIGHER lanes, scan idiom).
// bound_ctrl=false => invalid source lane (lane 0) keeps `old` operand.
__device__ __forceinline__ float dpp_shr1(float old0, float src) {
    int r = __builtin_amdgcn_update_dpp(__float_as_int(old0), __float_as_int(src),
                                        0x138, 0xf, 0xf, false);
    return __int_as_float(r);
}

// ---------------------------------------------------------------------------
// Kernel 1: MFMA cost GEMM. cost'[b][i][j] = max(0, ||x_i-y_j||^2)*log2(e), bf16.
// 128x128 tile / 256 thr = 4 waves (2x2 of 64x64). K=64 via 2x mfma 16x16x32.
// LDS rows padded to 72 shorts (144 B). C staged through LDS (aliased onto A/B)
// for coalesced dwordx4 global stores.
// ---------------------------------------------------------------------------
__global__ __launch_bounds__(256) void cost_gemm_mfma(const float* __restrict__ x,
                                                      const float* __restrict__ y,
                                                      unsigned short* __restrict__ cost) {
    __shared__ unsigned short SMEM[2 * 128 * 72];   // A | B, later aliased as C
    __shared__ float x2s[128];
    __shared__ float y2s[128];

    unsigned short* Al = SMEM;
    unsigned short* Bl = SMEM + 128 * 72;

    const int b   = blockIdx.z;
    const int i0  = blockIdx.y * 128;
    const int j0  = blockIdx.x * 128;
    const int tid = threadIdx.x;
    const int w   = tid >> 6;          // wave 0..3
    const int l   = tid & 63;
    const int wr  = w >> 1;            // wave row (i)
    const int wc  = w & 1;             // wave col (j)

    // ---- stage x,y (fp32 -> bf16) into LDS ----
    const float4* xt = (const float4*)(x + ((size_t)b * T_LEN + i0) * D_DIM);
    const float4* yt = (const float4*)(y + ((size_t)b * T_LEN + j0) * D_DIM);
    #pragma unroll
    for (int s = 0; s < 8; ++s) {
        int f   = tid + s * 256;       // float4 index 0..2047
        int row = f >> 4;
        int kk  = (f & 15) * 4;
        float4 va = xt[f];
        float4 vb = yt[f];
        unsigned a01 = (unsigned)f2bf_rne(va.x) | ((unsigned)f2bf_rne(va.y) << 16);
        unsigned a23 = (unsigned)f2bf_rne(va.z) | ((unsigned)f2bf_rne(va.w) << 16);
        unsigned b01 = (unsigned)f2bf_rne(vb.x) | ((unsigned)f2bf_rne(vb.y) << 16);
        unsigned b23 = (unsigned)f2bf_rne(vb.z) | ((unsigned)f2bf_rne(vb.w) << 16);
        *(uint2*)(Al + row * 72 + kk) = make_uint2(a01, a23);
        *(uint2*)(Bl + row * 72 + kk) = make_uint2(b01, b23);
    }
    __syncthreads();

    // ---- squared norms from the bf16 values (consistent with the dot) ----
    {
        const unsigned short* src = (tid < 128) ? Al : Bl;
        int row = tid & 127;
        float s = 0.f;
        #pragma unroll
        for (int q = 0; q < 8; ++q) {
            uint4 u = *(const uint4*)(src + row * 72 + q * 8);
            float e0 = bf_lo(u.x), e1 = bf_hi(u.x), e2 = bf_lo(u.y), e3 = bf_hi(u.y);
            float e4 = bf_lo(u.z), e5 = bf_hi(u.z), e6 = bf_lo(u.w), e7 = bf_hi(u.w);
            s = fmaf(e0, e0, s); s = fmaf(e1, e1, s);
            s = fmaf(e2, e2, s); s = fmaf(e3, e3, s);
            s = fmaf(e4, e4, s); s = fmaf(e5, e5, s);
            s = fmaf(e6, e6, s); s = fmaf(e7, e7, s);
        }
        if (tid < 128) x2s[row] = s; else y2s[row] = s;
    }

    // ---- fragment loads (A: rows of x-tile; B: rows of y-tile) ----
    // frag element j: k = kq*32 + (l>>4)*8 + j  -> byte m*144 + kq*64 + (l>>4)*16
    short8 af[4][2], bf[4][2];
    const int lq16 = (l >> 4) * 16;
    #pragma unroll
    for (int ti = 0; ti < 4; ++ti) {
        int m = wr * 64 + ti * 16 + (l & 15);
        #pragma unroll
        for (int kq = 0; kq < 2; ++kq)
            af[ti][kq] = *(const short8*)((const char*)Al + m * 144 + kq * 64 + lq16);
    }
    #pragma unroll
    for (int tj = 0; tj < 4; ++tj) {
        int n = wc * 64 + tj * 16 + (l & 15);
        #pragma unroll
        for (int kq = 0; kq < 2; ++kq)
            bf[tj][kq] = *(const short8*)((const char*)Bl + n * 144 + kq * 64 + lq16);
    }
    __syncthreads();   // everyone done reading A/B; SMEM now reusable as C

    floatx4 acc[4][4];
    #pragma unroll
    for (int ti = 0; ti < 4; ++ti)
        #pragma unroll
        for (int tj = 0; tj < 4; ++tj) {
            floatx4 a0 = {0.f, 0.f, 0.f, 0.f};
            a0 = __builtin_amdgcn_mfma_f32_16x16x32_bf16(af[ti][0], bf[tj][0], a0, 0, 0, 0);
            a0 = __builtin_amdgcn_mfma_f32_16x16x32_bf16(af[ti][1], bf[tj][1], a0, 0, 0, 0);
            acc[ti][tj] = a0;
        }

    // ---- epilogue: cost = max(0, x2 + y2 - 2*dot) * L2E -> bf16 -> LDS ----
    unsigned short* Cw = SMEM + w * (64 * 72);   // wave-private 64x72 region
    #pragma unroll
    for (int ti = 0; ti < 4; ++ti) {
        #pragma unroll
        for (int tj = 0; tj < 4; ++tj) {
            int nloc = tj * 16 + (l & 15);
            float y2v = y2s[wc * 64 + nloc];
            #pragma unroll
            for (int g = 0; g < 4; ++g) {
                int mloc = ti * 16 + (l >> 4) * 4 + g;
                float x2v = x2s[wr * 64 + mloc];
                float cv = fmaxf(0.f, x2v + y2v - 2.f * acc[ti][tj][g]) * L2E;
                Cw[mloc * 72 + nloc] = f2bf_rne(cv);
            }
        }
    }
    // own-wave data only -> no barrier needed; compiler orders LDS ops.
    #pragma unroll
    for (int p = 0; p < 8; ++p) {
        int r  = p * 8 + (l >> 3);
        int c0 = (l & 7) * 8;
        uint4 v = *(const uint4*)((const char*)Cw + r * 144 + c0 * 2);
        size_t off = ((size_t)b * T_LEN + (size_t)(i0 + wr * 64 + r)) * T_LEN
                   + (size_t)(j0 + wc * 64 + c0);
        *(uint4*)(cost + off) = v;
    }
}

// ---------------------------------------------------------------------------
// Kernel 2: systolic 8-wave pipeline per batch (512 thr = 2 waves/SIMD).
// Wave w owns rows 128w+1..128w+128 (2 rows/lane). Neighbor lane via DPP
// wave_shr:1 (no LDS latency; lane0 boundary select fused into `old`);
// inter-wave boundary via LDS history + flags, tight spin.
// State scaled by log2(e).
// ---------------------------------------------------------------------------
template<bool MASK, bool W0>
__device__ __forceinline__ void run_range(
    int cbeg, int cend, int l, int phi, int q0,
    const unsigned short* __restrict__ rp0,
    const unsigned short* __restrict__ rp1,
    uint4 (&Bq)[2], uint4 (&Nq)[2],
    float (&D1)[2], float (&D2)[2], int thr_base,
    float* __restrict__ bnd_out, const float* __restrict__ bnd_in,
    volatile int* flag_out, volatile int* flag_in)
{
    for (int c = cbeg; c < cend; ++c) {
        // prefetch quads for chunk c+1
        int qn = c + 1 - q0;
        qn = qn < 0 ? 0 : (qn > 127 ? 127 : qn);
        uint4 Pq0 = *(const uint4*)(rp0 + qn * 8);
        uint4 Pq1 = *(const uint4*)(rp1 + qn * 8);

        float pv[9];
        if (!W0) {
            int need = c + 17; if (need > NCHUNK) need = NCHUNK;
            while (*flag_in < need) { }          // tight spin
            __threadfence_block();
            #pragma unroll
            for (int j = 0; j < 9; ++j) pv[j] = bnd_in[8 * c + 126 + j];
        }

        float bval[8];
        #pragma unroll
        for (int s = 0; s < 8; ++s) {
            float a_in, b_in;
            if (W0) {
                a_in = (c == 0 && s == 0) ? 0.0f : BIG2;   // d_0[0]=0 enters at k=2
                b_in = BIG2;
            } else {
                a_in = pv[s];       // d_{k-2}[128w]
                b_in = pv[s + 1];   // d_{k-1}[128w]
            }
            float carry2 = dpp_shr1(a_in, D2[1]);
            float carry1 = dpp_shr1(b_in, D1[1]);

            #pragma unroll
            for (int r = 0; r < 2; ++r) {
                const int J0 = (8 + s - r) >> 1;     // 3..7, compile-time
                const int hf = (s - r) & 1;          // compile-time
                unsigned e0 = wsel(Bq[r], Nq[r], J0);
                unsigned e1 = wsel(Bq[r], Nq[r], J0 - 1);
                unsigned e2 = wsel(Bq[r], Nq[r], J0 - 2);
                unsigned e3 = wsel(Bq[r], Nq[r], J0 - 3);
                unsigned t0 = (phi & 1) ? e1 : e0;
                unsigned t1 = (phi & 1) ? e3 : e2;
                unsigned wsv = (phi & 2) ? t1 : t0;
                float cval = __uint_as_float(hf ? (wsv & 0xffff0000u) : (wsv << 16));

                float aa = carry2, bb = carry1, cc = D1[r];
                float m   = fminf(fminf(aa, bb), cc);
                float M   = fmaxf(fmaxf(aa, bb), cc);
                float mid = __builtin_amdgcn_fmed3f(aa, bb, cc);
                float ssum = 1.0f + FAST_EXP2(m - mid) + FAST_EXP2(m - M);
                float nv = cval + m - FAST_LOG2(ssum);
                if (MASK) nv = ((8 * c + s) <= (thr_base + r)) ? nv : BIG2;

                carry2 = D2[r];
                carry1 = cc;
                D2[r] = cc;
                D1[r] = nv;
            }
            bval[s] = D1[1];
        }

        if (bnd_out) {                     // wave < 7: publish boundary row
            if (l == 63) {
                #pragma unroll
                for (int s = 0; s < 8; ++s) bnd_out[8 * c + s] = bval[s];
            }
            __threadfence_block();
            if (l == 63) *flag_out = c + 1;
        }

        Bq[0] = Nq[0]; Bq[1] = Nq[1];
        Nq[0] = Pq0;   Nq[1] = Pq1;
    }
}

__global__ __launch_bounds__(512) void dp_pipe8(const unsigned short* __restrict__ cost,
                                                float* __restrict__ out) {
    __shared__ float Bnd[7][1280];   // [producer wave][k - (128w+2)], init BIG2
    __shared__ int   prog[8];

    const int b   = blockIdx.x;
    const int tid = threadIdx.x;
    const int w   = tid >> 6;        // wave 0..7
    const int l   = tid & 63;
    const int phi = l & 3;
    const int q0  = l >> 2;

    for (int j = tid; j < 7 * 1280; j += 512) ((float*)Bnd)[j] = BIG2;
    if (tid < 8) prog[tid] = 0;
    __syncthreads();                 // only barrier

    volatile int* progv = prog;

    const unsigned short* rp0 = cost + ((size_t)(b * T_LEN + 128 * w + 2 * l)) * T_LEN;
    const unsigned short* rp1 = rp0 + T_LEN;

    uint4 Bq[2], Nq[2];
    Nq[0] = *(const uint4*)rp0;      // quad 0 (clamped window start)
    Nq[1] = *(const uint4*)rp1;
    Bq[0] = Nq[0]; Bq[1] = Nq[1];

    float D1[2] = {BIG2, BIG2}, D2[2] = {BIG2, BIG2};
    const int thr_base = 2 * l + 1023;   // valid iff 8c+s <= thr_base + r

    float* bnd_out = (w < 7) ? Bnd[w] : nullptr;
    const float* bnd_in = (w > 0) ? Bnd[w - 1] : nullptr;
    volatile int* flag_out = &progv[w];
    volatile int* flag_in  = (w > 0) ? &progv[w - 1] : nullptr;

    if (w == 0) {
        run_range<false, true>(0, NOMASK_CHUNKS, l, phi, q0, rp0, rp1, Bq, Nq, D1, D2,
                               thr_base, bnd_out, bnd_in, flag_out, flag_in);
        run_range<true,  true>(NOMASK_CHUNKS, NCHUNK, l, phi, q0, rp0, rp1, Bq, Nq, D1, D2,
                               thr_base, bnd_out, bnd_in, flag_out, flag_in);
    } else {
        run_range<false, false>(0, NOMASK_CHUNKS, l, phi, q0, rp0, rp1, Bq, Nq, D1, D2,
                                thr_base, bnd_out, bnd_in, flag_out, flag_in);
        run_range<true,  false>(NOMASK_CHUNKS, NCHUNK, l, phi, q0, rp0, rp1, Bq, Nq, D1, D2,
                                thr_base, bnd_out, bnd_in, flag_out, flag_in);
    }

    // after k = 128*7+1153 = 2049: D1 = d_2049 (masked), D2 = d_2048.
    if (w == 7 && l == 63) out[b] = D2[1] * LN2F;   // d_2048[1024], descaled
}

// ---------------------------------------------------------------------------
// Fallback (no workspace): costs on the fly. Correct, slow.
// ---------------------------------------------------------------------------
__device__ __forceinline__ float softmin3_ref(float a, float b, float c) {
    float m = fminf(a, fminf(b, c));
    float s = FAST_EXP2((m - a) * L2E) + FAST_EXP2((m - b) * L2E) + FAST_EXP2((m - c) * L2E);
    return m - FAST_LOG2(s) * LN2F;
}

__global__ __launch_bounds__(1024) void dp_onthefly(const float* __restrict__ x,
                                                    const float* __restrict__ y,
                                                    float* __restrict__ out) {
    __shared__ float bufs[3][1026];
    __shared__ float y2s[1024];
    const int b   = blockIdx.x;
    const int tid = threadIdx.x;

    const float4* xrow = (const float4*)(x + ((size_t)b * T_LEN + (size_t)tid) * D_DIM);
    const float4* yb   = (const float4*)(y + (size_t)b * T_LEN * D_DIM);

    float4 xr[16];
    float x2 = 0.f;
    #pragma unroll
    for (int q = 0; q < 16; ++q) {
        xr[q] = xrow[q];
        x2 = fmaf(xr[q].x, xr[q].x, x2);
        x2 = fmaf(xr[q].y, xr[q].y, x2);
        x2 = fmaf(xr[q].z, xr[q].z, x2);
        x2 = fmaf(xr[q].w, xr[q].w, x2);
    }
    float y2 = 0.f;
    #pragma unroll
    for (int q = 0; q < 16; ++q) {
        float4 v = yb[tid * 16 + q];
        y2 = fmaf(v.x, v.x, y2); y2 = fmaf(v.y, v.y, y2);
        y2 = fmaf(v.z, v.z, y2); y2 = fmaf(v.w, v.w, y2);
    }
    y2s[tid] = y2;

    bufs[0][tid] = (tid == 0) ? 0.0f : BIGF;
    bufs[1][tid] = BIGF;
    if (tid == 0) { bufs[0][1024] = BIGF; bufs[1][1024] = BIGF; }
    __syncthreads();

    float* p2  = bufs[0];
    float* p1  = bufs[1];
    float* cur = bufs[2];

    for (int k = 2; k <= 2 * T_LEN; ++k) {
        const int col = k - tid - 2;
        float v = BIGF;
        if (col >= 0 && col < T_LEN) {
            const float4* yr = yb + (size_t)col * 16;
            float dot = 0.f;
            #pragma unroll
            for (int q = 0; q < 16; ++q) {
                float4 ww = yr[q];
                dot = fmaf(xr[q].x, ww.x, dot);
                dot = fmaf(xr[q].y, ww.y, dot);
                dot = fmaf(xr[q].z, ww.z, dot);
                dot = fmaf(xr[q].w, ww.w, dot);
            }
            float cval = fmaxf(0.f, x2 + y2s[col] - 2.f * dot);
            v = cval + softmin3_ref(p2[tid], p1[tid], p1[tid + 1]);
        }
        cur[tid + 1] = v;
        if (tid == 0) cur[0] = BIGF;
        __syncthreads();
        float* tmp = p2; p2 = p1; p1 = cur; cur = tmp;
    }
    if (tid == 0) out[b] = p1[1024];
}

extern "C" void kernel_launch(void* const* d_in, const int* in_sizes, int n_in,
                              void* d_out, int out_size, void* d_ws, size_t ws_size,
                              hipStream_t stream) {
    const float* x = (const float*)d_in[0];
    const float* y = (const float*)d_in[1];
    float* out = (float*)d_out;

    const size_t cost_bytes = (size_t)BATCH * T_LEN * T_LEN * sizeof(unsigned short); // 64 MiB

    if (ws_size >= cost_bytes) {
        unsigned short* cost = (unsigned short*)d_ws;
        dim3 grid(T_LEN / 128, T_LEN / 128, BATCH);   // 8 x 8 x 32
        cost_gemm_mfma<<<grid, 256, 0, stream>>>(x, y, cost);
        dp_pipe8<<<BATCH, 512, 0, stream>>>(cost, out);
    } else {
        dp_onthefly<<<BATCH, 1024, 0, stream>>>(x, y, out);
    }
}